// Round 5
// baseline (15460.587 us; speedup 1.0000x reference)
//
#include <hip/hip_runtime.h>
#include <hip/hip_bf16.h>

#define DEVINL __device__ __forceinline__

DEVINL float bf2f(unsigned short u) { return __uint_as_float(((unsigned)u) << 16); }
DEVINL unsigned short f2bf(float f) {            // round-to-nearest-even
  unsigned u = __float_as_uint(f);
  unsigned r = u + 0x7FFFu + ((u >> 16) & 1u);
  return (unsigned short)(r >> 16);
}

// typed 4-wide load/store (bf16-as-ushort or fp32), fp32 compute everywhere
DEVINL float4 ld4(const float* p) { return *(const float4*)p; }
DEVINL float4 ld4(const unsigned short* p) {
  ushort4 u = *(const ushort4*)p;
  return make_float4(bf2f(u.x), bf2f(u.y), bf2f(u.z), bf2f(u.w));
}
DEVINL void st4(float* p, float4 v) { *(float4*)p = v; }
DEVINL void st4(unsigned short* p, float4 v) {
  ushort4 u; u.x = f2bf(v.x); u.y = f2bf(v.y); u.z = f2bf(v.z); u.w = f2bf(v.w);
  *(ushort4*)p = u;
}
DEVINL float ld1(const float* p) { return *p; }
DEVINL float ld1(const unsigned short* p) { return bf2f(*p); }

// region: 0=center,1=TL,2=top,3=TR,4=right,5=BR,6=bottom,7=BL,8=left
DEVINL int region_of(int h, int w, int n) {
  if (h == 0)     return (w == 0) ? 1 : ((w == n-1) ? 3 : 2);
  if (h == n-1)   return (w == 0) ? 7 : ((w == n-1) ? 5 : 6);
  return (w == 0) ? 8 : ((w == n-1) ? 4 : 0);
}

// ---- sentinel: encodes an environment-assumption failure into d_out ----
__global__ void sentinel_k(float* out, float v) {
  int t = blockIdx.x*64 + threadIdx.x;
  if (t < 320) out[t] = v;
}

// ---- conv1: C=1 -> F=64, N=64, u-domain; fp32 x in, bf16 u1 out ----
__global__ __launch_bounds__(256) void conv1_k(const float* __restrict__ x,
    const float* __restrict__ Wf, const float* __restrict__ Df,
    unsigned short* __restrict__ out)
{
  int h = blockIdx.x, b = blockIdx.y, t = threadIdx.x;
  __shared__ float a[3][66];
  for (int idx = t; idx < 3*66; idx += 256) {
    int dy = idx / 66, wcol = idx % 66;
    int hh = h + dy - 1, w = wcol - 1;
    float v = 0.f;
    if (hh >= 0 && hh < 64 && w >= 0 && w < 64)
      v = x[(b*64 + hh)*64 + w];
    a[dy][wcol] = v;
  }
  __syncthreads();
  int f = t & 63, wq = t >> 6;   // 4 w-groups of 16
  float wk[9];
  #pragma unroll
  for (int k = 0; k < 9; k++) wk[k] = Wf[k*64 + f];
  for (int wi = 0; wi < 16; wi++) {
    int w = wq*16 + wi;
    float acc = 0.f;
    #pragma unroll
    for (int dy = 0; dy < 3; dy++)
      #pragma unroll
      for (int dx = 0; dx < 3; dx++)
        acc += a[dy][w+dx] * wk[dy*3+dx];
    int r = region_of(h, w, 64);
    out[((b*64 + h)*64 + w)*64 + f] = f2bf(fminf(acc - Df[r*64 + f], 0.f));
  }
}

// ---- generic u-domain conv: NHWC, fp32 compute, typed in/out ----
// block = one (b,h) row; 256 threads; 4w x 4f register tile per thread
template<int C, int F, int N, typename TI, typename TO>
__global__ __launch_bounds__(256) void convk(const TI* __restrict__ in,
    const float* __restrict__ Wf, const float* __restrict__ Df,
    TO* __restrict__ out)
{
  int h = blockIdx.x, b = blockIdx.y, t = threadIdx.x;
  __shared__ float a[3*(N+2)*C];
  // interior staging, zero rows outside image (u-domain zero padding)
  const int body4 = 3*N*C/4;
  for (int idx4 = t; idx4 < body4; idx4 += 256) {
    int idx = idx4 * 4;
    int dy = idx / (N*C), rem = idx % (N*C);
    int w = rem / C, c = rem % C;
    int hh = h + dy - 1;
    float4 v = make_float4(0.f,0.f,0.f,0.f);
    if (hh >= 0 && hh < N)
      v = ld4(&in[((b*N + hh)*N + w)*C + c]);
    *(float4*)&a[(dy*(N+2) + (w+1))*C + c] = v;
  }
  // halo columns = 0
  for (int idx4 = t; idx4 < 3*2*C/4; idx4 += 256) {
    int idx = idx4 * 4;
    int dy = idx / (2*C), rem = idx % (2*C);
    int side = rem / C, c = rem % C;
    *(float4*)&a[(dy*(N+2) + (side ? (N+1) : 0))*C + c] = make_float4(0.f,0.f,0.f,0.f);
  }
  __syncthreads();

  constexpr int FG = F/4;
  int f0 = (t % FG) * 4, w0 = (t / FG) * 4;
  float acc[4][4] = {};
  #pragma unroll
  for (int dy = 0; dy < 3; dy++)
  #pragma unroll
  for (int dx = 0; dx < 3; dx++) {
    const float* ap = &a[(dy*(N+2) + (w0+dx))*C];
    const float* wp = &Wf[(dy*3+dx)*C*F + f0];
    for (int c = 0; c < C; c += 4) {
      float4 av[4], wv[4];
      #pragma unroll
      for (int i = 0; i < 4; i++) av[i] = *(const float4*)(ap + i*C + c);
      #pragma unroll
      for (int cc = 0; cc < 4; cc++) wv[cc] = *(const float4*)(wp + (c+cc)*F);
      #pragma unroll
      for (int cc = 0; cc < 4; cc++) {
        #pragma unroll
        for (int i = 0; i < 4; i++) {
          float af = ((const float*)&av[i])[cc];
          acc[i][0] += af * wv[cc].x;
          acc[i][1] += af * wv[cc].y;
          acc[i][2] += af * wv[cc].z;
          acc[i][3] += af * wv[cc].w;
        }
      }
    }
  }
  #pragma unroll
  for (int i = 0; i < 4; i++) {
    int w = w0 + i;
    int r = region_of(h, w, N);
    float4 v;
    v.x = fminf(acc[i][0] - Df[r*F + f0+0], 0.f);
    v.y = fminf(acc[i][1] - Df[r*F + f0+1], 0.f);
    v.z = fminf(acc[i][2] - Df[r*F + f0+2], 0.f);
    v.w = fminf(acc[i][3] - Df[r*F + f0+3], 0.f);
    st4(&out[((b*N + h)*N + w)*F + f0], v);
  }
}

// ---- 2x2 max pool (exact in u-domain) ----
template<int N, int C, typename TI, typename TO>
__global__ void poolk(const TI* __restrict__ in, TO* __restrict__ out) {
  constexpr int M = N/2;
  int i = blockIdx.x*256 + threadIdx.x;
  if (i >= 32*M*M*C) return;
  int c = i % C, w = (i/C) % M, hh = (i/(C*M)) % M, b = i/(C*M*M);
  const TI* p = in + ((b*N + 2*hh)*N + 2*w)*C + c;
  float m = fmaxf(fmaxf(ld1(p), ld1(p+C)), fmaxf(ld1(p+N*C), ld1(p+(N+1)*C)));
  if (sizeof(TO) == 2) ((unsigned short*)out)[i] = f2bf(m); else ((float*)out)[i] = m;
}

// ---- dense1 split-K: act fp32 [32,32768], Wd1 fp32 [32768,256] -> partials ----
__global__ __launch_bounds__(256) void dense_k(const float* __restrict__ act,
    const float* __restrict__ W, float* __restrict__ part)
{
  int blk = blockIdx.x, t = threadIdx.x;   // 256 blocks, k-chunk 128
  int k0 = blk * 128;
  __shared__ float a[128][36];             // [kc][b], padded
  for (int idx = t; idx < 32*128; idx += 256) {
    int b = idx >> 7, kc = idx & 127;
    a[kc][b] = act[b*32768 + k0 + kc];
  }
  __syncthreads();
  int f0 = (t & 63) * 4, b0 = (t >> 6) * 8;  // 4f x 8b per thread
  float acc[8][4] = {};
  for (int kc = 0; kc < 128; kc++) {
    float4 wv = *(const float4*)&W[(k0 + kc)*256 + f0];
    #pragma unroll
    for (int bb = 0; bb < 8; bb++) {
      float av = a[kc][b0 + bb];
      acc[bb][0] += av * wv.x;
      acc[bb][1] += av * wv.y;
      acc[bb][2] += av * wv.z;
      acc[bb][3] += av * wv.w;
    }
  }
  for (int bb = 0; bb < 8; bb++) {
    float4 v = make_float4(acc[bb][0], acc[bb][1], acc[bb][2], acc[bb][3]);
    *(float4*)&part[blk*8192 + (b0+bb)*256 + f0] = v;
  }
}

__global__ void reduce_k(const float* __restrict__ part, const float* __restrict__ Dd,
                         float* __restrict__ ud)
{
  int i = blockIdx.x*256 + threadIdx.x;   // 8192 = 32b x 256f
  float s = 0.f;
  #pragma unroll 4
  for (int blk = 0; blk < 256; blk++) s += part[blk*8192 + i];
  ud[i] = fminf(s - Dd[i & 255], 0.f);
}

// ---- output: out[b,o] = Dout[o] - sum_f ud[b,f]*Wout[f,o]; fp32 out ----
__global__ void final_k(const float* __restrict__ ud, const float* __restrict__ Wo,
                        const float* __restrict__ Do, float* __restrict__ out)
{
  int t = blockIdx.x*64 + threadIdx.x;
  if (t >= 320) return;
  int b = t / 10, o = t % 10;
  float acc = 0.f;
  for (int f = 0; f < 256; f++) acc += ud[b*256 + f] * Wo[f*10 + o];
  out[t] = Do[o] - acc;
}

extern "C" void kernel_launch(void* const* d_in, const int* in_sizes, int n_in,
                              void* d_out, int out_size, void* d_ws, size_t ws_size,
                              hipStream_t stream)
{
  float* outp = (float*)d_out;

  // --- environment asserts with sentinel outputs ---
  if (n_in != 13) { sentinel_k<<<5, 64, 0, stream>>>(outp, 200.f); return; }
  const int exp_sz[13] = {131072, 576, 576, 36864, 576, 73728, 1152,
                          147456, 1152, 8388608, 256, 2560, 10};
  for (int i = 0; i < 13; i++)
    if (in_sizes[i] != exp_sz[i]) {
      sentinel_k<<<5, 64, 0, stream>>>(outp, 1000.f + 100.f*i); return;
    }
  if (ws_size < (37u << 20)) { sentinel_k<<<5, 64, 0, stream>>>(outp, 500.f); return; }

  char* wsb = (char*)d_ws;
  const float* x    = (const float*)d_in[0];
  const float* Wc1  = (const float*)d_in[1];
  const float* Dc1  = (const float*)d_in[2];
  const float* Wc2  = (const float*)d_in[3];
  const float* Dc2  = (const float*)d_in[4];
  const float* Wc3  = (const float*)d_in[5];
  const float* Dc3  = (const float*)d_in[6];
  const float* Wc4  = (const float*)d_in[7];
  const float* Dc4  = (const float*)d_in[8];
  const float* Wd1  = (const float*)d_in[9];
  const float* Dd1  = (const float*)d_in[10];
  const float* Wout = (const float*)d_in[11];
  const float* Dout = (const float*)d_in[12];

  // ws layout (lifetime-safe; peak ~36 MiB):
  //   [0,1 MiB): ud (32 KB)
  //   A = [2,19 MiB), B = [19,36 MiB)
  float* ud = (float*)wsb;
  unsigned short* U1 = (unsigned short*)(wsb + (2u  << 20)); // u1 bf16 16.78 MB
  unsigned short* U2 = (unsigned short*)(wsb + (19u << 20)); // u2 bf16 16.78 MB
  float* P2   = (float*)(wsb + (2u  << 20));  // p2 fp32 8.39 MB (U1 dead)
  float* U3   = (float*)(wsb + (19u << 20));  // u3 fp32 16.78 MB (U2 dead)
  float* U4   = (float*)(wsb + (2u  << 20));  // u4 fp32 16.78 MB (P2 dead)
  float* P4   = (float*)(wsb + (19u << 20));  // p4 fp32 4.19 MB (U3 dead)
  float* part = (float*)(wsb + (2u  << 20));  // 8.39 MB (U4 dead)

  conv1_k<<<dim3(64, 32), 256, 0, stream>>>(x, Wc1, Dc1, U1);
  convk<64, 64, 64, unsigned short, unsigned short>
      <<<dim3(64, 32), 256, 0, stream>>>(U1, Wc2, Dc2, U2);
  poolk<64, 64, unsigned short, float><<<8192, 256, 0, stream>>>(U2, P2);
  convk<64, 128, 32, float, float>
      <<<dim3(32, 32), 256, 0, stream>>>(P2, Wc3, Dc3, U3);
  convk<128, 128, 32, float, float>
      <<<dim3(32, 32), 256, 0, stream>>>(U3, Wc4, Dc4, U4);
  poolk<32, 128, float, float><<<4096, 256, 0, stream>>>(U4, P4);
  dense_k<<<256, 256, 0, stream>>>(P4, Wd1, part);
  reduce_k<<<32, 256, 0, stream>>>(part, Dd1, ud);
  final_k<<<5, 64, 0, stream>>>(ud, Wout, Dout, outp);
}

// Round 6
// 266.496 us; speedup vs baseline: 58.0144x; 58.0144x over previous
//
#include <hip/hip_runtime.h>
#include <hip/hip_bf16.h>

#define DEVINL __device__ __forceinline__

typedef __attribute__((ext_vector_type(8)))  short short8;
typedef __attribute__((ext_vector_type(4)))  float float4v;

DEVINL float bf2f(unsigned short u) { return __uint_as_float(((unsigned)u) << 16); }
DEVINL unsigned short f2bf(float f) {            // round-to-nearest-even
  unsigned u = __float_as_uint(f);
  unsigned r = u + 0x7FFFu + ((u >> 16) & 1u);
  return (unsigned short)(r >> 16);
}

// region: 0=center,1=TL,2=top,3=TR,4=right,5=BR,6=bottom,7=BL,8=left
DEVINL int region_of(int h, int w, int n) {
  if (h == 0)     return (w == 0) ? 1 : ((w == n-1) ? 3 : 2);
  if (h == n-1)   return (w == 0) ? 7 : ((w == n-1) ? 5 : 6);
  return (w == 0) ? 8 : ((w == n-1) ? 4 : 0);
}

// ---- sentinel: encodes an environment-assumption failure into d_out ----
__global__ void sentinel_k(float* out, float v) {
  int t = blockIdx.x*64 + threadIdx.x;
  if (t < 320) out[t] = v;
}

// ---- weight transpose into MFMA B-fragment layout, fp32 -> bf16 ----
// B-frag (16x16x32): lane holds B[k = (lane>>4)*8 + j][n = lane&15], j=0..7.
// Wt[((kstep*NT + nt)*64 + lane)*8 + j] = bf16(W[kstep*32 + (lane>>4)*8 + j][nt*16 + (lane&15)])
__global__ void wtrans_k(const float* __restrict__ W, unsigned short* __restrict__ Wt,
                         int Ksteps, int NT, int F)
{
  int i = blockIdx.x*256 + threadIdx.x;
  if (i >= Ksteps*NT*64) return;
  int lane = i & 63, nt = (i >> 6) % NT, kstep = i / (64*NT);
  int f = nt*16 + (lane & 15);
  int kbase = kstep*32 + (lane >> 4)*8;
  unsigned short v[8];
  #pragma unroll
  for (int j = 0; j < 8; j++) v[j] = f2bf(W[(kbase + j)*F + f]);
  ushort4* q = (ushort4*)&Wt[(size_t)i * 8];
  q[0] = make_ushort4(v[0], v[1], v[2], v[3]);
  q[1] = make_ushort4(v[4], v[5], v[6], v[7]);
}

// ---- conv1: C=1 -> F=64, N=64, u-domain; fp32 x in, bf16 u1 out (vector ALU) ----
__global__ __launch_bounds__(256) void conv1_k(const float* __restrict__ x,
    const float* __restrict__ Wf, const float* __restrict__ Df,
    unsigned short* __restrict__ out)
{
  int h = blockIdx.x, b = blockIdx.y, t = threadIdx.x;
  __shared__ float a[3][66];
  for (int idx = t; idx < 3*66; idx += 256) {
    int dy = idx / 66, wcol = idx % 66;
    int hh = h + dy - 1, w = wcol - 1;
    float v = 0.f;
    if (hh >= 0 && hh < 64 && w >= 0 && w < 64)
      v = x[(b*64 + hh)*64 + w];
    a[dy][wcol] = v;
  }
  __syncthreads();
  int f = t & 63, wq = t >> 6;
  float wk[9];
  #pragma unroll
  for (int k = 0; k < 9; k++) wk[k] = Wf[k*64 + f];
  for (int wi = 0; wi < 16; wi++) {
    int w = wq*16 + wi;
    float acc = 0.f;
    #pragma unroll
    for (int dy = 0; dy < 3; dy++)
      #pragma unroll
      for (int dx = 0; dx < 3; dx++)
        acc += a[dy][w+dx] * wk[dy*3+dx];
    int r = region_of(h, w, 64);
    out[((b*64 + h)*64 + w)*64 + f] = f2bf(fminf(acc - Df[r*64 + f], 0.f));
  }
}

// ---- MFMA u-domain conv: bf16 NHWC in/out, fp32 accum ----
// Implicit GEMM: M = w positions, N = F, K = 9*C. mfma_f32_16x16x32_bf16.
// Block = (b, chunk of HCH output rows); 4 waves.
//   conv2 (C=64,F=64,N=64):  MT=4 m-tiles/wave, 1 n-tile/wave (wave = ntile)
//   conv3/4 (F=128,N=32):    MT=2, 2 n-tiles/wave
template<int C, int F, int N, int HCH>
__global__ __launch_bounds__(256) void conv_mfma(
    const unsigned short* __restrict__ U, const unsigned short* __restrict__ Wt,
    const float* __restrict__ Df, unsigned short* __restrict__ out)
{
  constexpr int Cpad = C + 4;          // (Cpad*2)/4 % 32 == 2 -> conflict-free
  constexpr int ROWS = HCH + 2;
  constexpr int NT = F / 16;           // n-tiles total
  constexpr int MT = N / 16;           // m-tiles total (all owned by each wave)
  constexpr int WNT = NT / 4;          // n-tiles per wave
  constexpr int KST = 9*C/32;          // K-steps of 32

  __shared__ unsigned short lds[ROWS*(N+2)*Cpad];

  int b = blockIdx.y, h0 = blockIdx.x * HCH, t = threadIdx.x;

  // stage ROWS input rows (bf16 copy, zero halo)
  const int stage8 = ROWS*(N+2)*(C/8);
  for (int i = t; i < stage8; i += 256) {
    int c8 = i % (C/8), wc = (i/(C/8)) % (N+2), r = i/((C/8)*(N+2));
    int hh = h0 - 1 + r, w = wc - 1;
    ushort4 v0 = make_ushort4(0,0,0,0), v1 = v0;
    if (hh >= 0 && hh < N && w >= 0 && w < N) {
      const ushort4* p = (const ushort4*)&U[(((size_t)b*N + hh)*N + w)*C + c8*8];
      v0 = p[0]; v1 = p[1];
    }
    unsigned short* q = &lds[(r*(N+2) + wc)*Cpad + c8*8];
    *(ushort4*)q = v0; *(ushort4*)(q+4) = v1;
  }
  __syncthreads();

  int lane = t & 63, wave = t >> 6;
  int quad = lane >> 4, lm = lane & 15;

  union ABu { ushort4 h[2]; short8 v; };

  for (int hi = 0; hi < HCH; hi++) {
    int h = h0 + hi;
    float4v acc[MT][WNT];
    #pragma unroll
    for (int m = 0; m < MT; m++)
      #pragma unroll
      for (int n = 0; n < WNT; n++)
        acc[m][n] = (float4v){0.f, 0.f, 0.f, 0.f};

    for (int dy = 0; dy < 3; dy++)
    for (int dx = 0; dx < 3; dx++)
    #pragma unroll 1
    for (int c0 = 0; c0 < C; c0 += 32) {
      int kstep = (dy*3 + dx)*(C/32) + (c0 >> 5);
      ABu afr[MT];
      #pragma unroll
      for (int m = 0; m < MT; m++) {
        const unsigned short* ap =
            &lds[((hi+dy)*(N+2) + (m*16 + lm + dx))*Cpad + c0 + quad*8];
        afr[m].h[0] = *(const ushort4*)ap;
        afr[m].h[1] = *(const ushort4*)(ap + 4);
      }
      #pragma unroll
      for (int n = 0; n < WNT; n++) {
        int nt = wave*WNT + n;
        ABu bfr;
        const ushort4* bp = (const ushort4*)&Wt[(size_t)((kstep*NT + nt)*64 + lane)*8];
        bfr.h[0] = bp[0]; bfr.h[1] = bp[1];
        #pragma unroll
        for (int m = 0; m < MT; m++)
          acc[m][n] = __builtin_amdgcn_mfma_f32_16x16x32_bf16(afr[m].v, bfr.v, acc[m][n], 0, 0, 0);
      }
    }

    // epilogue: D layout col=lane&15 (f), row=quad*4+r (w)
    #pragma unroll
    for (int m = 0; m < MT; m++)
      #pragma unroll
      for (int n = 0; n < WNT; n++) {
        int f = (wave*WNT + n)*16 + lm;
        #pragma unroll
        for (int r = 0; r < 4; r++) {
          int w = m*16 + quad*4 + r;
          int reg = region_of(h, w, N);
          float v = fminf(acc[m][n][r] - Df[reg*F + f], 0.f);
          out[(((size_t)b*N + h)*N + w)*F + f] = f2bf(v);
        }
      }
  }
}

// ---- 2x2 max pool (exact in u-domain), bf16 -> bf16 ----
template<int N, int C>
__global__ void poolk(const unsigned short* __restrict__ in, unsigned short* __restrict__ out) {
  constexpr int M = N/2;
  int i = blockIdx.x*256 + threadIdx.x;
  if (i >= 32*M*M*C) return;
  int c = i % C, w = (i/C) % M, hh = (i/(C*M)) % M, b = i/(C*M*M);
  const unsigned short* p = in + (((size_t)b*N + 2*hh)*N + 2*w)*C + c;
  float m = fmaxf(fmaxf(bf2f(p[0]), bf2f(p[C])), fmaxf(bf2f(p[N*C]), bf2f(p[(N+1)*C])));
  out[i] = f2bf(m);   // exact: inputs bf16-representable
}

// ---- dense1 split-K: act bf16 [32,32768], Wd1 fp32 [32768,256] -> fp32 partials ----
__global__ __launch_bounds__(256) void dense_k(const unsigned short* __restrict__ act,
    const float* __restrict__ W, float* __restrict__ part)
{
  int blk = blockIdx.x, t = threadIdx.x;   // 256 blocks, k-chunk 128
  int k0 = blk * 128;
  __shared__ float a[128][36];             // [kc][b], padded
  for (int idx = t; idx < 32*128; idx += 256) {
    int b = idx >> 7, kc = idx & 127;
    a[kc][b] = bf2f(act[(size_t)b*32768 + k0 + kc]);
  }
  __syncthreads();
  int f0 = (t & 63) * 4, b0 = (t >> 6) * 8;  // 4f x 8b per thread
  float acc[8][4] = {};
  for (int kc = 0; kc < 128; kc++) {
    float4 wv = *(const float4*)&W[(size_t)(k0 + kc)*256 + f0];
    #pragma unroll
    for (int bb = 0; bb < 8; bb++) {
      float av = a[kc][b0 + bb];
      acc[bb][0] += av * wv.x;
      acc[bb][1] += av * wv.y;
      acc[bb][2] += av * wv.z;
      acc[bb][3] += av * wv.w;
    }
  }
  for (int bb = 0; bb < 8; bb++) {
    float4 v = make_float4(acc[bb][0], acc[bb][1], acc[bb][2], acc[bb][3]);
    *(float4*)&part[(size_t)blk*8192 + (b0+bb)*256 + f0] = v;
  }
}

__global__ void reduce_k(const float* __restrict__ part, const float* __restrict__ Dd,
                         float* __restrict__ ud)
{
  int i = blockIdx.x*256 + threadIdx.x;   // 8192 = 32b x 256f
  float s = 0.f;
  #pragma unroll 4
  for (int blk = 0; blk < 256; blk++) s += part[(size_t)blk*8192 + i];
  ud[i] = fminf(s - Dd[i & 255], 0.f);
}

// ---- output: out[b,o] = Dout[o] - sum_f ud[b,f]*Wout[f,o]; fp32 out ----
__global__ void final_k(const float* __restrict__ ud, const float* __restrict__ Wo,
                        const float* __restrict__ Do, float* __restrict__ out)
{
  int t = blockIdx.x*64 + threadIdx.x;
  if (t >= 320) return;
  int b = t / 10, o = t % 10;
  float acc = 0.f;
  for (int f = 0; f < 256; f++) acc += ud[b*256 + f] * Wo[f*10 + o];
  out[t] = Do[o] - acc;
}

extern "C" void kernel_launch(void* const* d_in, const int* in_sizes, int n_in,
                              void* d_out, int out_size, void* d_ws, size_t ws_size,
                              hipStream_t stream)
{
  float* outp = (float*)d_out;

  // --- environment asserts with sentinel outputs (validated in R4/R5) ---
  if (n_in != 13) { sentinel_k<<<5, 64, 0, stream>>>(outp, 200.f); return; }
  const int exp_sz[13] = {131072, 576, 576, 36864, 576, 73728, 1152,
                          147456, 1152, 8388608, 256, 2560, 10};
  for (int i = 0; i < 13; i++)
    if (in_sizes[i] != exp_sz[i]) {
      sentinel_k<<<5, 64, 0, stream>>>(outp, 1000.f + 100.f*i); return;
    }
  if (ws_size < (37u << 20)) { sentinel_k<<<5, 64, 0, stream>>>(outp, 500.f); return; }

  char* wsb = (char*)d_ws;
  const float* x    = (const float*)d_in[0];
  const float* Wc1  = (const float*)d_in[1];
  const float* Dc1  = (const float*)d_in[2];
  const float* Wc2  = (const float*)d_in[3];
  const float* Dc2  = (const float*)d_in[4];
  const float* Wc3  = (const float*)d_in[5];
  const float* Dc3  = (const float*)d_in[6];
  const float* Wc4  = (const float*)d_in[7];
  const float* Dc4  = (const float*)d_in[8];
  const float* Wd1  = (const float*)d_in[9];
  const float* Dd1  = (const float*)d_in[10];
  const float* Wout = (const float*)d_in[11];
  const float* Dout = (const float*)d_in[12];

  // ws layout (lifetime-safe):
  //   [0, 32KB): ud | [1.0,1.8 MiB): Wt2/Wt3/Wt4 | A=[2,19 MiB) B=[19,36 MiB)
  float* ud = (float*)wsb;
  unsigned short* Wt2 = (unsigned short*)(wsb + (1u << 20));            // 73.7 KB
  unsigned short* Wt3 = (unsigned short*)(wsb + (1u << 20) + 262144);   // 147 KB
  unsigned short* Wt4 = (unsigned short*)(wsb + (1u << 20) + 524288);   // 295 KB
  unsigned short* U1 = (unsigned short*)(wsb + (2u  << 20)); // 16.78 MB
  unsigned short* U2 = (unsigned short*)(wsb + (19u << 20)); // 16.78 MB
  unsigned short* P2 = (unsigned short*)(wsb + (2u  << 20)); // 4.2 MB (U1 dead)
  unsigned short* U3 = (unsigned short*)(wsb + (19u << 20)); // 8.4 MB (U2 dead)
  unsigned short* U4 = (unsigned short*)(wsb + (2u  << 20)); // 8.4 MB (P2 dead)
  unsigned short* P4 = (unsigned short*)(wsb + (19u << 20)); // 2.1 MB (U3 dead)
  float* part        = (float*)(wsb + (2u  << 20));          // 8.4 MB (U4 dead)

  // weight transposes into B-frag layout (bf16)
  wtrans_k<<<(18*4*64 + 255)/256, 256, 0, stream>>>(Wc2, Wt2, 18, 4, 64);
  wtrans_k<<<(18*8*64 + 255)/256, 256, 0, stream>>>(Wc3, Wt3, 18, 8, 128);
  wtrans_k<<<(36*8*64 + 255)/256, 256, 0, stream>>>(Wc4, Wt4, 36, 8, 128);

  conv1_k<<<dim3(64, 32), 256, 0, stream>>>(x, Wc1, Dc1, U1);
  conv_mfma<64, 64, 64, 4><<<dim3(16, 32), 256, 0, stream>>>(U1, Wt2, Dc2, U2);
  poolk<64, 64><<<8192, 256, 0, stream>>>(U2, P2);
  conv_mfma<64, 128, 32, 4><<<dim3(8, 32), 256, 0, stream>>>(P2, Wt3, Dc3, U3);
  conv_mfma<128, 128, 32, 4><<<dim3(8, 32), 256, 0, stream>>>(U3, Wt4, Dc4, U4);
  poolk<32, 128><<<4096, 256, 0, stream>>>(U4, P4);
  dense_k<<<256, 256, 0, stream>>>(P4, Wd1, part);
  reduce_k<<<32, 256, 0, stream>>>(part, Dd1, ud);
  final_k<<<5, 64, 0, stream>>>(ud, Wout, Dout, outp);
}

// Round 7
// 214.612 us; speedup vs baseline: 72.0398x; 1.2418x over previous
//
#include <hip/hip_runtime.h>
#include <hip/hip_bf16.h>

#define DEVINL __device__ __forceinline__

typedef __attribute__((ext_vector_type(8)))  short short8;
typedef __attribute__((ext_vector_type(4)))  float float4v;

DEVINL float bf2f(unsigned short u) { return __uint_as_float(((unsigned)u) << 16); }
DEVINL unsigned short f2bf(float f) {            // round-to-nearest-even
  unsigned u = __float_as_uint(f);
  unsigned r = u + 0x7FFFu + ((u >> 16) & 1u);
  return (unsigned short)(r >> 16);
}

// region: 0=center,1=TL,2=top,3=TR,4=right,5=BR,6=bottom,7=BL,8=left
DEVINL int region_of(int h, int w, int n) {
  if (h == 0)     return (w == 0) ? 1 : ((w == n-1) ? 3 : 2);
  if (h == n-1)   return (w == 0) ? 7 : ((w == n-1) ? 5 : 6);
  return (w == 0) ? 8 : ((w == n-1) ? 4 : 0);
}

// ---- sentinel: encodes an environment-assumption failure into d_out ----
__global__ void sentinel_k(float* out, float v) {
  int t = blockIdx.x*64 + threadIdx.x;
  if (t < 320) out[t] = v;
}

// ---- weight transpose into MFMA B-fragment layout, fp32 -> bf16 ----
// B-frag (16x16x32): lane holds B[k = (lane>>4)*8 + j][n = lane&15], j=0..7.
__global__ void wtrans_k(const float* __restrict__ W, unsigned short* __restrict__ Wt,
                         int Ksteps, int NT, int F)
{
  int i = blockIdx.x*256 + threadIdx.x;
  if (i >= Ksteps*NT*64) return;
  int lane = i & 63, nt = (i >> 6) % NT, kstep = i / (64*NT);
  int f = nt*16 + (lane & 15);
  int kbase = kstep*32 + (lane >> 4)*8;
  unsigned short v[8];
  #pragma unroll
  for (int j = 0; j < 8; j++) v[j] = f2bf(W[(kbase + j)*F + f]);
  ushort4* q = (ushort4*)&Wt[(size_t)i * 8];
  q[0] = make_ushort4(v[0], v[1], v[2], v[3]);
  q[1] = make_ushort4(v[4], v[5], v[6], v[7]);
}

// ---- conv1: C=1 -> F=64, N=64, u-domain; fp32 x in, bf16 u1 out (vector ALU) ----
__global__ __launch_bounds__(256) void conv1_k(const float* __restrict__ x,
    const float* __restrict__ Wf, const float* __restrict__ Df,
    unsigned short* __restrict__ out)
{
  int h = blockIdx.x, b = blockIdx.y, t = threadIdx.x;
  __shared__ float a[3][66];
  for (int idx = t; idx < 3*66; idx += 256) {
    int dy = idx / 66, wcol = idx % 66;
    int hh = h + dy - 1, w = wcol - 1;
    float v = 0.f;
    if (hh >= 0 && hh < 64 && w >= 0 && w < 64)
      v = x[(b*64 + hh)*64 + w];
    a[dy][wcol] = v;
  }
  __syncthreads();
  int f = t & 63, wq = t >> 6;
  float wk[9];
  #pragma unroll
  for (int k = 0; k < 9; k++) wk[k] = Wf[k*64 + f];
  for (int wi = 0; wi < 16; wi++) {
    int w = wq*16 + wi;
    float acc = 0.f;
    #pragma unroll
    for (int dy = 0; dy < 3; dy++)
      #pragma unroll
      for (int dx = 0; dx < 3; dx++)
        acc += a[dy][w+dx] * wk[dy*3+dx];
    int r = region_of(h, w, 64);
    out[((b*64 + h)*64 + w)*64 + f] = f2bf(fminf(acc - Df[r*64 + f], 0.f));
  }
}

// ---- MFMA u-domain conv: bf16 NHWC in/out, fp32 accum ----
// Implicit GEMM: M = w positions, N = F, K = 9*C. mfma_f32_16x16x32_bf16.
// Block = (b, ONE output row h); 3 input rows staged; 4 waves.
// Grid = N x 32 blocks -> 1024-2048 blocks (R6 fix: was 256 blocks = 1/CU,
// 9.5% occupancy, MfmaUtil 6.5% -- pure latency-bound).
template<int C, int F, int N>
__global__ __launch_bounds__(256) void conv_mfma(
    const unsigned short* __restrict__ U, const unsigned short* __restrict__ Wt,
    const float* __restrict__ Df, unsigned short* __restrict__ out)
{
  constexpr int Cpad = C + 8;          // mult of 8 -> 16B-aligned ds_read_b128,
                                       // bank pattern 4*(lm+quad)%32: uniform
  constexpr int NT = F / 16;           // n-tiles total
  constexpr int MT = N / 16;           // m-tiles (all owned by each wave)
  constexpr int WNT = NT / 4;          // n-tiles per wave

  __shared__ __align__(16) unsigned short lds[3*(N+2)*Cpad];

  int b = blockIdx.y, h = blockIdx.x, t = threadIdx.x;

  // stage rows h-1,h,h+1 (16B chunks, zero halo)
  const int stage16 = 3*(N+2)*(C/8);
  for (int i = t; i < stage16; i += 256) {
    int c8 = i % (C/8), wc = (i/(C/8)) % (N+2), r = i/((C/8)*(N+2));
    int hh = h - 1 + r, w = wc - 1;
    float4 v = make_float4(0.f,0.f,0.f,0.f);
    if (hh >= 0 && hh < N && w >= 0 && w < N)
      v = *(const float4*)&U[(((size_t)b*N + hh)*N + w)*C + c8*8];
    *(float4*)&lds[(r*(N+2) + wc)*Cpad + c8*8] = v;
  }
  __syncthreads();

  int lane = t & 63, wave = t >> 6;
  int quad = lane >> 4, lm = lane & 15;

  union ABu { float4 f4; short8 v; };

  float4v acc[MT][WNT];
  #pragma unroll
  for (int m = 0; m < MT; m++)
    #pragma unroll
    for (int n = 0; n < WNT; n++)
      acc[m][n] = (float4v){0.f, 0.f, 0.f, 0.f};

  #pragma unroll
  for (int dy = 0; dy < 3; dy++)
  #pragma unroll
  for (int dx = 0; dx < 3; dx++)
  for (int c0 = 0; c0 < C; c0 += 32) {
    int kstep = (dy*3 + dx)*(C/32) + (c0 >> 5);
    ABu bfr[WNT];
    #pragma unroll
    for (int n = 0; n < WNT; n++)
      bfr[n].f4 = *(const float4*)&Wt[(size_t)((kstep*NT + wave*WNT + n)*64 + lane)*8];
    ABu afr[MT];
    #pragma unroll
    for (int m = 0; m < MT; m++)
      afr[m].f4 = *(const float4*)&lds[(dy*(N+2) + (m*16 + lm + dx))*Cpad + c0 + quad*8];
    #pragma unroll
    for (int n = 0; n < WNT; n++)
      #pragma unroll
      for (int m = 0; m < MT; m++)
        acc[m][n] = __builtin_amdgcn_mfma_f32_16x16x32_bf16(afr[m].v, bfr[n].v, acc[m][n], 0, 0, 0);
  }

  // epilogue: D layout col=lane&15 (f), row=quad*4+r (w)
  #pragma unroll
  for (int m = 0; m < MT; m++)
    #pragma unroll
    for (int n = 0; n < WNT; n++) {
      int f = (wave*WNT + n)*16 + lm;
      #pragma unroll
      for (int r = 0; r < 4; r++) {
        int w = m*16 + quad*4 + r;
        int reg = region_of(h, w, N);
        float v = fminf(acc[m][n][r] - Df[reg*F + f], 0.f);
        out[(((size_t)b*N + h)*N + w)*F + f] = f2bf(v);
      }
    }
}

// ---- 2x2 max pool (exact in u-domain), bf16 -> bf16 ----
template<int N, int C>
__global__ void poolk(const unsigned short* __restrict__ in, unsigned short* __restrict__ out) {
  constexpr int M = N/2;
  int i = blockIdx.x*256 + threadIdx.x;
  if (i >= 32*M*M*C) return;
  int c = i % C, w = (i/C) % M, hh = (i/(C*M)) % M, b = i/(C*M*M);
  const unsigned short* p = in + (((size_t)b*N + 2*hh)*N + 2*w)*C + c;
  float m = fmaxf(fmaxf(bf2f(p[0]), bf2f(p[C])), fmaxf(bf2f(p[N*C]), bf2f(p[(N+1)*C])));
  out[i] = f2bf(m);   // exact: inputs bf16-representable
}

// ---- dense1 split-K: act bf16 [32,32768], Wd1 fp32 [32768,256] -> fp32 partials ----
__global__ __launch_bounds__(256) void dense_k(const unsigned short* __restrict__ act,
    const float* __restrict__ W, float* __restrict__ part)
{
  int blk = blockIdx.x, t = threadIdx.x;   // 256 blocks, k-chunk 128
  int k0 = blk * 128;
  __shared__ float a[128][36];             // [kc][b], padded
  for (int idx = t; idx < 32*128; idx += 256) {
    int b = idx >> 7, kc = idx & 127;
    a[kc][b] = bf2f(act[(size_t)b*32768 + k0 + kc]);
  }
  __syncthreads();
  int f0 = (t & 63) * 4, b0 = (t >> 6) * 8;  // 4f x 8b per thread
  float acc[8][4] = {};
  for (int kc = 0; kc < 128; kc++) {
    float4 wv = *(const float4*)&W[(size_t)(k0 + kc)*256 + f0];
    #pragma unroll
    for (int bb = 0; bb < 8; bb++) {
      float av = a[kc][b0 + bb];
      acc[bb][0] += av * wv.x;
      acc[bb][1] += av * wv.y;
      acc[bb][2] += av * wv.z;
      acc[bb][3] += av * wv.w;
    }
  }
  for (int bb = 0; bb < 8; bb++) {
    float4 v = make_float4(acc[bb][0], acc[bb][1], acc[bb][2], acc[bb][3]);
    *(float4*)&part[(size_t)blk*8192 + (b0+bb)*256 + f0] = v;
  }
}

__global__ void reduce_k(const float* __restrict__ part, const float* __restrict__ Dd,
                         float* __restrict__ ud)
{
  int i = blockIdx.x*256 + threadIdx.x;   // 8192 = 32b x 256f
  float s = 0.f;
  #pragma unroll 4
  for (int blk = 0; blk < 256; blk++) s += part[(size_t)blk*8192 + i];
  ud[i] = fminf(s - Dd[i & 255], 0.f);
}

// ---- output: out[b,o] = Dout[o] - sum_f ud[b,f]*Wout[f,o]; fp32 out ----
__global__ void final_k(const float* __restrict__ ud, const float* __restrict__ Wo,
                        const float* __restrict__ Do, float* __restrict__ out)
{
  int t = blockIdx.x*64 + threadIdx.x;
  if (t >= 320) return;
  int b = t / 10, o = t % 10;
  float acc = 0.f;
  for (int f = 0; f < 256; f++) acc += ud[b*256 + f] * Wo[f*10 + o];
  out[t] = Do[o] - acc;
}

extern "C" void kernel_launch(void* const* d_in, const int* in_sizes, int n_in,
                              void* d_out, int out_size, void* d_ws, size_t ws_size,
                              hipStream_t stream)
{
  float* outp = (float*)d_out;

  // --- environment asserts with sentinel outputs (validated in R4/R5) ---
  if (n_in != 13) { sentinel_k<<<5, 64, 0, stream>>>(outp, 200.f); return; }
  const int exp_sz[13] = {131072, 576, 576, 36864, 576, 73728, 1152,
                          147456, 1152, 8388608, 256, 2560, 10};
  for (int i = 0; i < 13; i++)
    if (in_sizes[i] != exp_sz[i]) {
      sentinel_k<<<5, 64, 0, stream>>>(outp, 1000.f + 100.f*i); return;
    }
  if (ws_size < (37u << 20)) { sentinel_k<<<5, 64, 0, stream>>>(outp, 500.f); return; }

  char* wsb = (char*)d_ws;
  const float* x    = (const float*)d_in[0];
  const float* Wc1  = (const float*)d_in[1];
  const float* Dc1  = (const float*)d_in[2];
  const float* Wc2  = (const float*)d_in[3];
  const float* Dc2  = (const float*)d_in[4];
  const float* Wc3  = (const float*)d_in[5];
  const float* Dc3  = (const float*)d_in[6];
  const float* Wc4  = (const float*)d_in[7];
  const float* Dc4  = (const float*)d_in[8];
  const float* Wd1  = (const float*)d_in[9];
  const float* Dd1  = (const float*)d_in[10];
  const float* Wout = (const float*)d_in[11];
  const float* Dout = (const float*)d_in[12];

  // ws layout (lifetime-safe):
  //   [0, 32KB): ud | [1.0,1.8 MiB): Wt2/Wt3/Wt4 | A=[2,19 MiB) B=[19,36 MiB)
  float* ud = (float*)wsb;
  unsigned short* Wt2 = (unsigned short*)(wsb + (1u << 20));            // 73.7 KB
  unsigned short* Wt3 = (unsigned short*)(wsb + (1u << 20) + 262144);   // 147 KB
  unsigned short* Wt4 = (unsigned short*)(wsb + (1u << 20) + 524288);   // 295 KB
  unsigned short* U1 = (unsigned short*)(wsb + (2u  << 20)); // 16.78 MB
  unsigned short* U2 = (unsigned short*)(wsb + (19u << 20)); // 16.78 MB
  unsigned short* P2 = (unsigned short*)(wsb + (2u  << 20)); // 4.2 MB (U1 dead)
  unsigned short* U3 = (unsigned short*)(wsb + (19u << 20)); // 8.4 MB (U2 dead)
  unsigned short* U4 = (unsigned short*)(wsb + (2u  << 20)); // 8.4 MB (P2 dead)
  unsigned short* P4 = (unsigned short*)(wsb + (19u << 20)); // 2.1 MB (U3 dead)
  float* part        = (float*)(wsb + (2u  << 20));          // 8.4 MB (U4 dead)

  // weight transposes into B-frag layout (bf16)
  wtrans_k<<<(18*4*64 + 255)/256, 256, 0, stream>>>(Wc2, Wt2, 18, 4, 64);
  wtrans_k<<<(18*8*64 + 255)/256, 256, 0, stream>>>(Wc3, Wt3, 18, 8, 128);
  wtrans_k<<<(36*8*64 + 255)/256, 256, 0, stream>>>(Wc4, Wt4, 36, 8, 128);

  conv1_k<<<dim3(64, 32), 256, 0, stream>>>(x, Wc1, Dc1, U1);
  conv_mfma<64, 64, 64><<<dim3(64, 32), 256, 0, stream>>>(U1, Wt2, Dc2, U2);
  poolk<64, 64><<<8192, 256, 0, stream>>>(U2, P2);
  conv_mfma<64, 128, 32><<<dim3(32, 32), 256, 0, stream>>>(P2, Wt3, Dc3, U3);
  conv_mfma<128, 128, 32><<<dim3(32, 32), 256, 0, stream>>>(U3, Wt4, Dc4, U4);
  poolk<32, 128><<<4096, 256, 0, stream>>>(U4, P4);
  dense_k<<<256, 256, 0, stream>>>(P4, Wd1, part);
  reduce_k<<<32, 256, 0, stream>>>(part, Dd1, ud);
  final_k<<<5, 64, 0, stream>>>(ud, Wout, Dout, outp);
}

// Round 8
// 194.228 us; speedup vs baseline: 79.6000x; 1.1049x over previous
//
#include <hip/hip_runtime.h>
#include <hip/hip_bf16.h>

#define DEVINL __device__ __forceinline__

typedef __attribute__((ext_vector_type(8)))  short short8;
typedef __attribute__((ext_vector_type(4)))  float float4v;

DEVINL float bf2f(unsigned short u) { return __uint_as_float(((unsigned)u) << 16); }
DEVINL unsigned short f2bf(float f) {            // round-to-nearest-even
  unsigned u = __float_as_uint(f);
  unsigned r = u + 0x7FFFu + ((u >> 16) & 1u);
  return (unsigned short)(r >> 16);
}

// region: 0=center,1=TL,2=top,3=TR,4=right,5=BR,6=bottom,7=BL,8=left
DEVINL int region_of(int h, int w, int n) {
  if (h == 0)     return (w == 0) ? 1 : ((w == n-1) ? 3 : 2);
  if (h == n-1)   return (w == 0) ? 7 : ((w == n-1) ? 5 : 6);
  return (w == 0) ? 8 : ((w == n-1) ? 4 : 0);
}

// ---- sentinel: encodes an environment-assumption failure into d_out ----
__global__ void sentinel_k(float* out, float v) {
  int t = blockIdx.x*64 + threadIdx.x;
  if (t < 320) out[t] = v;
}

// ---- weight transpose into MFMA B-fragment layout, fp32 -> bf16 (3 tensors) ----
// B-frag (16x16x32): lane holds B[k = (lane>>4)*8 + j][n = lane&15], j=0..7.
__global__ void wtrans_all(const float* __restrict__ W2, const float* __restrict__ W3,
                           const float* __restrict__ W4,
                           unsigned short* __restrict__ T2, unsigned short* __restrict__ T3,
                           unsigned short* __restrict__ T4)
{
  int y = blockIdx.y;
  const float* W = (y == 0) ? W2 : (y == 1) ? W3 : W4;
  unsigned short* T = (y == 0) ? T2 : (y == 1) ? T3 : T4;
  int Ksteps = (y == 2) ? 36 : 18;
  int NT = (y == 0) ? 4 : 8;
  int F  = (y == 0) ? 64 : 128;
  int i = blockIdx.x*256 + threadIdx.x;
  if (i >= Ksteps*NT*64) return;
  int lane = i & 63, nt = (i >> 6) % NT, kstep = i / (64*NT);
  int f = nt*16 + (lane & 15);
  int kbase = kstep*32 + (lane >> 4)*8;
  unsigned short v[8];
  #pragma unroll
  for (int j = 0; j < 8; j++) v[j] = f2bf(W[(kbase + j)*F + f]);
  ushort4* q = (ushort4*)&T[(size_t)i * 8];
  q[0] = make_ushort4(v[0], v[1], v[2], v[3]);
  q[1] = make_ushort4(v[4], v[5], v[6], v[7]);
}

// ---- conv1: C=1 -> F=64, N=64, u-domain; fp32 x in, bf16 u1 out (vector ALU) ----
__global__ __launch_bounds__(256) void conv1_k(const float* __restrict__ x,
    const float* __restrict__ Wf, const float* __restrict__ Df,
    unsigned short* __restrict__ out)
{
  int h = blockIdx.x, b = blockIdx.y, t = threadIdx.x;
  __shared__ float a[3][66];
  for (int idx = t; idx < 3*66; idx += 256) {
    int dy = idx / 66, wcol = idx % 66;
    int hh = h + dy - 1, w = wcol - 1;
    float v = 0.f;
    if (hh >= 0 && hh < 64 && w >= 0 && w < 64)
      v = x[(b*64 + hh)*64 + w];
    a[dy][wcol] = v;
  }
  __syncthreads();
  int f = t & 63, wq = t >> 6;
  float wk[9];
  #pragma unroll
  for (int k = 0; k < 9; k++) wk[k] = Wf[k*64 + f];
  for (int wi = 0; wi < 16; wi++) {
    int w = wq*16 + wi;
    float acc = 0.f;
    #pragma unroll
    for (int dy = 0; dy < 3; dy++)
      #pragma unroll
      for (int dx = 0; dx < 3; dx++)
        acc += a[dy][w+dx] * wk[dy*3+dx];
    int r = region_of(h, w, 64);
    out[((b*64 + h)*64 + w)*64 + f] = f2bf(fminf(acc - Df[r*64 + f], 0.f));
  }
}

// ---- MFMA u-domain conv (+ optional fused 2x2 pool): bf16 NHWC, fp32 accum ----
// Implicit GEMM: M = w positions, N = F, K = 9*C. mfma_f32_16x16x32_bf16.
// POOL=false: block = (b, one output row h), writes u.
// POOL=true:  block = (b, pooled row hp), computes u rows 2hp,2hp+1, writes
//             pooled row directly (pool pairs are register/lane-local).
template<int C, int F, int N, bool POOL>
__global__ __launch_bounds__(256) void conv_mfma(
    const unsigned short* __restrict__ U, const unsigned short* __restrict__ Wt,
    const float* __restrict__ Df, unsigned short* __restrict__ out)
{
  constexpr int RC   = POOL ? 2 : 1;   // rows computed
  constexpr int ROWS = RC + 2;         // rows staged
  constexpr int Cpad = C + 8;          // mult of 8: 16B-aligned ds_read_b128
  constexpr int NT = F / 16;
  constexpr int MT = N / 16;
  constexpr int WNT = NT / 4;

  __shared__ __align__(16) unsigned short lds[ROWS*(N+2)*Cpad];

  int b = blockIdx.y, hp = blockIdx.x, t = threadIdx.x;
  int h0 = hp * RC;

  // stage rows h0-1 .. h0+RC (16B chunks, zero halo)
  const int stage16 = ROWS*(N+2)*(C/8);
  for (int i = t; i < stage16; i += 256) {
    int c8 = i % (C/8), wc = (i/(C/8)) % (N+2), r = i/((C/8)*(N+2));
    int hh = h0 - 1 + r, w = wc - 1;
    float4 v = make_float4(0.f,0.f,0.f,0.f);
    if (hh >= 0 && hh < N && w >= 0 && w < N)
      v = *(const float4*)&U[(((size_t)b*N + hh)*N + w)*C + c8*8];
    *(float4*)&lds[(r*(N+2) + wc)*Cpad + c8*8] = v;
  }
  __syncthreads();

  int lane = t & 63, wave = t >> 6;
  int quad = lane >> 4, lm = lane & 15;

  union ABu { float4 f4; short8 v; };

  float4v acc[RC][MT][WNT];
  #pragma unroll
  for (int hi = 0; hi < RC; hi++)
    #pragma unroll
    for (int m = 0; m < MT; m++)
      #pragma unroll
      for (int n = 0; n < WNT; n++)
        acc[hi][m][n] = (float4v){0.f, 0.f, 0.f, 0.f};

  #pragma unroll
  for (int dy = 0; dy < 3; dy++)
  #pragma unroll
  for (int dx = 0; dx < 3; dx++)
  for (int c0 = 0; c0 < C; c0 += 32) {
    int kstep = (dy*3 + dx)*(C/32) + (c0 >> 5);
    ABu bfr[WNT];
    #pragma unroll
    for (int n = 0; n < WNT; n++)
      bfr[n].f4 = *(const float4*)&Wt[(size_t)((kstep*NT + wave*WNT + n)*64 + lane)*8];
    #pragma unroll
    for (int hi = 0; hi < RC; hi++) {
      ABu afr[MT];
      #pragma unroll
      for (int m = 0; m < MT; m++)
        afr[m].f4 = *(const float4*)&lds[((hi+dy)*(N+2) + (m*16 + lm + dx))*Cpad + c0 + quad*8];
      #pragma unroll
      for (int n = 0; n < WNT; n++)
        #pragma unroll
        for (int m = 0; m < MT; m++)
          acc[hi][m][n] = __builtin_amdgcn_mfma_f32_16x16x32_bf16(afr[m].v, bfr[n].v, acc[hi][m][n], 0, 0, 0);
    }
  }

  // epilogue: D layout col=lane&15 (f), row=quad*4+r (w)
  if (POOL) {
    constexpr int M2 = N/2;
    #pragma unroll
    for (int m = 0; m < MT; m++)
      #pragma unroll
      for (int n = 0; n < WNT; n++) {
        int f = (wave*WNT + n)*16 + lm;
        #pragma unroll
        for (int rp = 0; rp < 2; rp++) {
          float mx = -1e30f;
          #pragma unroll
          for (int hi = 0; hi < 2; hi++)
            #pragma unroll
            for (int rr = 0; rr < 2; rr++) {
              int h = h0 + hi, w = m*16 + quad*4 + 2*rp + rr;
              float v = fminf(acc[hi][m][n][2*rp+rr] - Df[region_of(h, w, N)*F + f], 0.f);
              mx = fmaxf(mx, v);
            }
          int wp = m*8 + quad*2 + rp;
          out[(((size_t)b*M2 + hp)*M2 + wp)*F + f] = f2bf(mx);
        }
      }
  } else {
    int h = h0;
    #pragma unroll
    for (int m = 0; m < MT; m++)
      #pragma unroll
      for (int n = 0; n < WNT; n++) {
        int f = (wave*WNT + n)*16 + lm;
        #pragma unroll
        for (int r = 0; r < 4; r++) {
          int w = m*16 + quad*4 + r;
          int reg = region_of(h, w, N);
          float v = fminf(acc[0][m][n][r] - Df[reg*F + f], 0.f);
          out[(((size_t)b*N + h)*N + w)*F + f] = f2bf(v);
        }
      }
  }
}

// ---- dense1 split-K + f-split: act bf16 [32,32768], Wd1 fp32 -> fp32 partials ----
// 512 blocks = 256 k-chunks x 2 f-halves (R7: 256 blocks = 1 wave/SIMD left
// ds_read latency unhidden).
__global__ __launch_bounds__(256) void dense_k(const unsigned short* __restrict__ act,
    const float* __restrict__ W, float* __restrict__ part)
{
  int blk = blockIdx.x, t = threadIdx.x;
  int kblk = blk >> 1, fh = blk & 1;
  int k0 = kblk * 128;
  __shared__ float a[128][36];             // [kc][b], padded
  for (int idx = t; idx < 32*128; idx += 256) {
    int bb = idx >> 7, kc = idx & 127;
    a[kc][bb] = bf2f(act[(size_t)bb*32768 + k0 + kc]);
  }
  __syncthreads();
  int f0 = fh*128 + (t & 31)*4, b0 = (t >> 5)*4;   // 4f x 4b per thread
  float acc[4][4] = {};
  for (int kc = 0; kc < 128; kc++) {
    float4 wv = *(const float4*)&W[(size_t)(k0 + kc)*256 + f0];
    #pragma unroll
    for (int bb = 0; bb < 4; bb++) {
      float av = a[kc][b0 + bb];
      acc[bb][0] += av * wv.x;
      acc[bb][1] += av * wv.y;
      acc[bb][2] += av * wv.z;
      acc[bb][3] += av * wv.w;
    }
  }
  #pragma unroll
  for (int bb = 0; bb < 4; bb++) {
    float4 v = make_float4(acc[bb][0], acc[bb][1], acc[bb][2], acc[bb][3]);
    *(float4*)&part[(size_t)kblk*8192 + (b0+bb)*256 + f0] = v;
  }
}

__global__ void reduce_k(const float* __restrict__ part, const float* __restrict__ Dd,
                         float* __restrict__ ud)
{
  int i = blockIdx.x*256 + threadIdx.x;   // 8192 = 32b x 256f
  float s = 0.f;
  #pragma unroll 4
  for (int blk = 0; blk < 256; blk++) s += part[(size_t)blk*8192 + i];
  ud[i] = fminf(s - Dd[i & 255], 0.f);
}

// ---- output: out[b,o] = Dout[o] - sum_f ud[b,f]*Wout[f,o]; fp32 out ----
__global__ void final_k(const float* __restrict__ ud, const float* __restrict__ Wo,
                        const float* __restrict__ Do, float* __restrict__ out)
{
  int t = blockIdx.x*64 + threadIdx.x;
  if (t >= 320) return;
  int b = t / 10, o = t % 10;
  float acc = 0.f;
  for (int f = 0; f < 256; f++) acc += ud[b*256 + f] * Wo[f*10 + o];
  out[t] = Do[o] - acc;
}

extern "C" void kernel_launch(void* const* d_in, const int* in_sizes, int n_in,
                              void* d_out, int out_size, void* d_ws, size_t ws_size,
                              hipStream_t stream)
{
  float* outp = (float*)d_out;

  // --- environment asserts with sentinel outputs (validated in R4/R5) ---
  if (n_in != 13) { sentinel_k<<<5, 64, 0, stream>>>(outp, 200.f); return; }
  const int exp_sz[13] = {131072, 576, 576, 36864, 576, 73728, 1152,
                          147456, 1152, 8388608, 256, 2560, 10};
  for (int i = 0; i < 13; i++)
    if (in_sizes[i] != exp_sz[i]) {
      sentinel_k<<<5, 64, 0, stream>>>(outp, 1000.f + 100.f*i); return;
    }
  if (ws_size < (37u << 20)) { sentinel_k<<<5, 64, 0, stream>>>(outp, 500.f); return; }

  char* wsb = (char*)d_ws;
  const float* x    = (const float*)d_in[0];
  const float* Wc1  = (const float*)d_in[1];
  const float* Dc1  = (const float*)d_in[2];
  const float* Wc2  = (const float*)d_in[3];
  const float* Dc2  = (const float*)d_in[4];
  const float* Wc3  = (const float*)d_in[5];
  const float* Dc3  = (const float*)d_in[6];
  const float* Wc4  = (const float*)d_in[7];
  const float* Dc4  = (const float*)d_in[8];
  const float* Wd1  = (const float*)d_in[9];
  const float* Dd1  = (const float*)d_in[10];
  const float* Wout = (const float*)d_in[11];
  const float* Dout = (const float*)d_in[12];

  // ws layout (lifetime-safe):
  //   [0,32KB): ud | [1.0,1.8 MiB): Wt2/Wt3/Wt4 | A=[2,19 MiB) B=[19,36 MiB)
  float* ud = (float*)wsb;
  unsigned short* Wt2 = (unsigned short*)(wsb + (1u << 20));
  unsigned short* Wt3 = (unsigned short*)(wsb + (1u << 20) + 262144);
  unsigned short* Wt4 = (unsigned short*)(wsb + (1u << 20) + 524288);
  unsigned short* U1 = (unsigned short*)(wsb + (2u  << 20)); // 16.78 MB
  unsigned short* P2 = (unsigned short*)(wsb + (19u << 20)); // 4.2 MB (conv2+pool out)
  unsigned short* U3 = (unsigned short*)(wsb + (2u  << 20)); // 8.4 MB (U1 dead)
  unsigned short* P4 = (unsigned short*)(wsb + (19u << 20)); // 2.1 MB (P2 dead)
  float* part        = (float*)(wsb + (2u  << 20));          // 8.4 MB (U3 dead)

  wtrans_all<<<dim3(72, 3), 256, 0, stream>>>(Wc2, Wc3, Wc4, Wt2, Wt3, Wt4);
  conv1_k<<<dim3(64, 32), 256, 0, stream>>>(x, Wc1, Dc1, U1);
  conv_mfma<64, 64, 64, true><<<dim3(32, 32), 256, 0, stream>>>(U1, Wt2, Dc2, P2);
  conv_mfma<64, 128, 32, false><<<dim3(32, 32), 256, 0, stream>>>(P2, Wt3, Dc3, U3);
  conv_mfma<128, 128, 32, true><<<dim3(16, 32), 256, 0, stream>>>(U3, Wt4, Dc4, P4);
  dense_k<<<512, 256, 0, stream>>>(P4, Wd1, part);
  reduce_k<<<32, 256, 0, stream>>>(part, Dd1, ud);
  final_k<<<5, 64, 0, stream>>>(ud, Wout, Dout, outp);
}